// Round 13
// baseline (860.790 us; speedup 1.0000x reference)
//
#include <hip/hip_runtime.h>
#include <math.h>

// Problem constants (from reference setup_inputs)
constexpr int Bq = 32;
constexpr int Tq = 8192;
constexpr int Dq = 8;
constexpr int Qq = 8;
constexpr int Kq = 1024;
constexpr int NTOK = Bq * Tq;                         // 262144 tokens
constexpr float LOSS_SCALE = 0.25f / (float)(Bq * Tq * Dq);

typedef __attribute__((ext_vector_type(8))) short short8;   // 8 bf16 (4 VGPRs)
typedef __attribute__((ext_vector_type(4))) float f32x4;
typedef __attribute__((ext_vector_type(4))) unsigned int u32x4;

// Round 13: MFMA dot products + margin-guarded exact fallback.
// Dekker 2-way bf16 split: r = rh + rl + O(2^-17 r), c = ch + cl + O(2^-17 c).
// One mfma_f32_16x16x32_bf16 packs all 4 cross terms into the 4 K-groups
// (A quad q: q&1 ? rl : rh ; B quad q: q>=2 ? cl : ch) -> approx dot with
// |err| <= ~1.6e-5*(rn+cn) vs the exact fp32 chain. Track per-token global
// top-2 (lex (d2,k) merged); if B2 <= B1 + (1e-4*rn + 5e-3) -- >=2.5x the
// bound, and covers exact ties -- the wave cooperatively rescans all 1024 k
// with the bit-exact R12 chain (16 k/lane, global L2-hot codebook), giving
// np.argmin first-min semantics unconditionally.
// C/D layout (m89-verified): col = lane&15, row = (lane>>4)*4 + reg.
__global__ __launch_bounds__(512, 2)
void rvq_main(const float* __restrict__ x,
              const float* __restrict__ codebooks,
              const float* __restrict__ post_scale,
              const float* __restrict__ post_bias,
              const float* __restrict__ conv_w,
              const float* __restrict__ conv_b,
              float* __restrict__ out)
{
    __shared__ __align__(16) float s_frag[Kq * 8];  // 32 KB: per cw, bf16x8 hi | bf16x8 lo
    __shared__ float s_cn[Kq];                      // 4 KB fp32 norms

    const int tid  = threadIdx.x;                  // 0..511
    const int lane = tid & 63;
    const int wave = tid >> 6;                     // 0..7
    const int quad = lane >> 4;                    // 0..3  (K-group)
    const int col  = lane & 15;                    // MFMA n / token idx
    const int selo = quad >> 1;                    // B half: 0=hi(ch) 1=lo(cl)
    const int wbase = blockIdx.x * 256 + wave * 32;

    // residuals: lane owns token wbase + g*16 + col for g=0,1 (dup x4 quads)
    float rg[2][Dq];
#pragma unroll
    for (int g = 0; g < 2; ++g) {
        const float4* xp = reinterpret_cast<const float4*>(
            x + (size_t)(wbase + g * 16 + col) * Dq);
        float4 a = xp[0], b = xp[1];
        rg[g][0]=a.x; rg[g][1]=a.y; rg[g][2]=a.z; rg[g][3]=a.w;
        rg[g][4]=b.x; rg[g][5]=b.y; rg[g][6]=b.z; rg[g][7]=b.w;
    }

    float qso[2][Dq];
#pragma unroll
    for (int g = 0; g < 2; ++g)
#pragma unroll
        for (int d = 0; d < Dq; ++d) qso[g][d] = 0.0f;
    float lossacc = 0.0f;

    float* out_quant = out;                               // [B*T*D]
    float* out_loss  = out + (size_t)NTOK * Dq;           // [1]
    float* out_codes = out_loss + 1;                      // [Q*B*T] as float

    for (int q = 0; q < Qq; ++q) {
        const float* cbq = codebooks + (size_t)q * Kq * Dq;

        // ---- stage: bf16 hi/lo B-fragments + fp32 norms (np order) ----
#pragma unroll
        for (int it = 0; it < 2; ++it) {
            int n = tid + it * 512;
            const float4* cp = reinterpret_cast<const float4*>(cbq + (size_t)n * 8);
            float4 ca = cp[0], cc = cp[1];
            float c[8] = {ca.x, ca.y, ca.z, ca.w, cc.x, cc.y, cc.z, cc.w};
            float nn = __fmul_rn(c[0], c[0]);
#pragma unroll
            for (int d = 1; d < 8; ++d)
                nn = __fadd_rn(nn, __fmul_rn(c[d], c[d]));
            s_cn[n] = nn;
            unsigned hb[8], lb[8];
#pragma unroll
            for (int d = 0; d < 8; ++d) {
                union { float f; unsigned u; } v; v.f = c[d];
                hb[d] = (v.u + 0x7FFFu + ((v.u >> 16) & 1u)) >> 16;   // RNE bf16
                union { unsigned u; float f; } h; h.u = hb[d] << 16;
                union { float f; unsigned u; } w; w.f = __fsub_rn(c[d], h.f); // exact
                lb[d] = (w.u + 0x7FFFu + ((w.u >> 16) & 1u)) >> 16;
            }
            u32x4 wh = {hb[0] | (hb[1] << 16), hb[2] | (hb[3] << 16),
                        hb[4] | (hb[5] << 16), hb[6] | (hb[7] << 16)};
            u32x4 wl = {lb[0] | (lb[1] << 16), lb[2] | (lb[3] << 16),
                        lb[4] | (lb[5] << 16), lb[6] | (lb[7] << 16)};
            reinterpret_cast<u32x4*>(s_frag)[n * 2]     = wh;
            reinterpret_cast<u32x4*>(s_frag)[n * 2 + 1] = wl;
        }
        __syncthreads();

        // ---- per-lane prep: rn (np order), split, A-fragments ----
        float rn_own[2];
        short8 afrag[2];
#pragma unroll
        for (int g = 0; g < 2; ++g) {
            float n = __fmul_rn(rg[g][0], rg[g][0]);
#pragma unroll
            for (int d = 1; d < 8; ++d)
                n = __fadd_rn(n, __fmul_rn(rg[g][d], rg[g][d]));
            rn_own[g] = n;
            short8 af;
#pragma unroll
            for (int d = 0; d < 8; ++d) {
                union { float f; unsigned u; } v; v.f = rg[g][d];
                unsigned hbb = (v.u + 0x7FFFu + ((v.u >> 16) & 1u)) >> 16;
                union { unsigned u; float f; } h; h.u = hbb << 16;
                union { float f; unsigned u; } w; w.f = __fsub_rn(rg[g][d], h.f);
                unsigned lbb = (w.u + 0x7FFFu + ((w.u >> 16) & 1u)) >> 16;
                af[d] = (short)((quad & 1) ? lbb : hbb);   // A: odd quads = lo
            }
            afrag[g] = af;
        }
        float s_rnv[2][4];        // rn of token row = quad*4 + reg
#pragma unroll
        for (int g = 0; g < 2; ++g)
#pragma unroll
            for (int rr = 0; rr < 4; ++rr)
                s_rnv[g][rr] = __shfl(rn_own[g], quad * 4 + rr, 64);

        // ---- MFMA tile loop: 64 tiles of 16 cw; 2 token-groups per B-load ----
        float b1[2][4], b2[2][4];
        int   k1[2][4];
#pragma unroll
        for (int g = 0; g < 2; ++g)
#pragma unroll
            for (int rr = 0; rr < 4; ++rr) {
                b1[g][rr] = __builtin_inff(); b2[g][rr] = __builtin_inff();
                k1[g][rr] = 0;
            }

        const f32x4* fragp = reinterpret_cast<const f32x4*>(s_frag);
#pragma unroll 2
        for (int tile = 0; tile < Kq / 16; ++tile) {
            f32x4 braw = fragp[(tile * 16 + col) * 2 + selo];
            short8 bfrag = __builtin_bit_cast(short8, braw);
            float cnv = s_cn[tile * 16 + col];
            int cand = tile * 16 + col;
#pragma unroll
            for (int g = 0; g < 2; ++g) {
                f32x4 acc = {0.f, 0.f, 0.f, 0.f};
                acc = __builtin_amdgcn_mfma_f32_16x16x32_bf16(afrag[g], bfrag, acc, 0, 0, 0);
#pragma unroll
                for (int reg = 0; reg < 4; ++reg) {
                    float d2 = fmaf(acc[reg], -2.0f, __fadd_rn(s_rnv[g][reg], cnv));
                    bool c1 = d2 < b1[g][reg];
                    float nb2 = c1 ? b1[g][reg] : fminf(b2[g][reg], d2);
                    k1[g][reg] = c1 ? cand : k1[g][reg];
                    b1[g][reg] = c1 ? d2 : b1[g][reg];
                    b2[g][reg] = nb2;
                }
            }
        }

        // ---- merge 16 cols per token (lex (d2,k)); flag near-ties ----
        int kf[2][4];
#pragma unroll
        for (int g = 0; g < 2; ++g)
#pragma unroll
            for (int reg = 0; reg < 4; ++reg) {
                float B1 = b1[g][reg], B2 = b2[g][reg];
                int K1 = k1[g][reg];
#pragma unroll
                for (int m = 1; m <= 8; m <<= 1) {
                    float o1 = __shfl_xor(B1, m, 64);
                    float o2 = __shfl_xor(B2, m, 64);
                    int   ok = __shfl_xor(K1, m, 64);
                    bool ow = (o1 < B1) || (o1 == B1 && ok < K1);
                    float nb2 = ow ? fminf(B1, o2) : fminf(o1, B2);
                    B1 = ow ? o1 : B1; K1 = ow ? ok : K1; B2 = nb2;
                }
                float margin = fmaf(s_rnv[g][reg], 1e-4f, 5e-3f);
                bool flg = (B2 <= __fadd_rn(B1, margin));
                kf[g][reg] = K1 | (flg ? (int)0x80000000 : 0);
            }

        // ---- route result to owner lanes (token idx == col) ----
        int bk[2], fl[2];
#pragma unroll
        for (int g = 0; g < 2; ++g) {
            int src = (col >> 2) * 16;     // quad-group holding rows col&~3
            int t0 = __shfl(kf[g][0], src, 64);
            int t1 = __shfl(kf[g][1], src, 64);
            int t2 = __shfl(kf[g][2], src, 64);
            int t3 = __shfl(kf[g][3], src, 64);
            int ta = (col & 1) ? t1 : t0;
            int tb = (col & 1) ? t3 : t2;
            int tv = (col & 2) ? tb : ta;
            fl[g] = (tv >> 31) & 1;
            bk[g] = tv & 0x7FFFFFFF;
        }

        // ---- rare: wave-cooperative EXACT rescan (bit-exact R12 chain) ----
#pragma unroll
        for (int g = 0; g < 2; ++g) {
            unsigned long long msk = __ballot(fl[g] && (lane < 16));
            while (msk) {
                int p = __builtin_ctzll(msk); msk &= (msk - 1);
                float rt[8];
#pragma unroll
                for (int d = 0; d < 8; ++d) rt[d] = __shfl(rg[g][d], p, 64);
                float rnt = __shfl(rn_own[g], p, 64);
                float bb = __builtin_inff(); int bkk = 0;
#pragma unroll 2
                for (int i = 0; i < 16; ++i) {
                    int k = lane + 64 * i;
                    const float4* cp = reinterpret_cast<const float4*>(cbq + (size_t)k * 8);
                    float4 ca = cp[0], cc = cp[1];
                    float dot = __fmul_rn(rt[0], ca.x);
                    dot = fmaf(rt[1], ca.y, dot);
                    dot = fmaf(rt[2], ca.z, dot);
                    dot = fmaf(rt[3], ca.w, dot);
                    dot = fmaf(rt[4], cc.x, dot);
                    dot = fmaf(rt[5], cc.y, dot);
                    dot = fmaf(rt[6], cc.z, dot);
                    dot = fmaf(rt[7], cc.w, dot);
                    float d2 = fmaf(dot, -2.0f, __fadd_rn(rnt, s_cn[k]));
                    if (d2 < bb) { bb = d2; bkk = k; }     // k ascending in-lane
                }
#pragma unroll
                for (int mm = 1; mm <= 32; mm <<= 1) {
                    float ob = __shfl_xor(bb, mm, 64);
                    int   ok = __shfl_xor(bkk, mm, 64);
                    if (ob < bb || (ob == bb && ok < bkk)) { bb = ob; bkk = ok; }
                }
                if (col == p) bk[g] = bkk;                 // np first-min, exact
            }
        }

        // ---- codes, exact update (np chains, fp32 codebook from global) ----
        const float sc = post_scale[q];
        const float bi = post_bias[q];
#pragma unroll
        for (int g = 0; g < 2; ++g) {
            if (lane < 16)
                out_codes[(size_t)q * NTOK + wbase + g * 16 + col] = (float)bk[g];
            const float4* ep = reinterpret_cast<const float4*>(cbq + (size_t)bk[g] * 8);
            float4 ea = ep[0], eb = ep[1];
            float e[8] = {ea.x, ea.y, ea.z, ea.w, eb.x, eb.y, eb.z, eb.w};
#pragma unroll
            for (int d = 0; d < 8; ++d) {
                float rd = rg[g][d];
                float est = __fadd_rn(rd, __fsub_rn(e[d], rd));
                qso[g][d] = __fadd_rn(__fadd_rn(qso[g][d], __fmul_rn(est, sc)), bi);
                float nr = __fsub_rn(rd, e[d]);
                float df = __fsub_rn(nr, e[d]);
                if (lane < 16) lossacc = fmaf(df, df, lossacc);
                rg[g][d] = nr;
            }
        }
        __syncthreads();   // all s_frag/s_cn reads done before next q restages
    }

    // ---- 1x1 conv epilogue: owner lanes (lane<16) write their 2 tokens ----
    if (lane < 16) {
#pragma unroll
        for (int g = 0; g < 2; ++g) {
            float o[8];
#pragma unroll
            for (int e2 = 0; e2 < 8; ++e2) {
                float acc = __fmul_rn(qso[g][0], conv_w[e2 * 8 + 0]);
#pragma unroll
                for (int d = 1; d < 8; ++d)
                    acc = fmaf(qso[g][d], conv_w[e2 * 8 + d], acc);
                o[e2] = __fadd_rn(acc, conv_b[e2]);
            }
            float4* op = reinterpret_cast<float4*>(
                out_quant + (size_t)(wbase + g * 16 + col) * Dq);
            op[0] = make_float4(o[0], o[1], o[2], o[3]);
            op[1] = make_float4(o[4], o[5], o[6], o[7]);
        }
    }

    // ---- loss reduction (lane<16 contributed; rest are 0) ----
    float v = lossacc;
#pragma unroll
    for (int off = 32; off >= 1; off >>= 1)
        v += __shfl_xor(v, off, 64);
    if (lane == 0)
        atomicAdd(out_loss, v * LOSS_SCALE);
}

extern "C" void kernel_launch(void* const* d_in, const int* in_sizes, int n_in,
                              void* d_out, int out_size, void* d_ws, size_t ws_size,
                              hipStream_t stream) {
    const float* x     = (const float*)d_in[0];
    const float* cb    = (const float*)d_in[1];
    const float* ps    = (const float*)d_in[2];
    const float* pb    = (const float*)d_in[3];
    const float* cw    = (const float*)d_in[4];
    const float* cbias = (const float*)d_in[5];
    float* out = (float*)d_out;

    // zero the loss accumulator slot (d_out is poisoned before every call)
    hipMemsetAsync(out + (size_t)NTOK * Dq, 0, sizeof(float), stream);

    rvq_main<<<dim3(NTOK / 256), dim3(512), 0, stream>>>(
        x, cb, ps, pb, cw, cbias, out);
}

// Round 14
// 807.116 us; speedup vs baseline: 1.0665x; 1.0665x over previous
//
#include <hip/hip_runtime.h>
#include <math.h>

// Problem constants (from reference setup_inputs)
constexpr int Bq = 32;
constexpr int Tq = 8192;
constexpr int Dq = 8;
constexpr int Qq = 8;
constexpr int Kq = 1024;
constexpr int NTOK = Bq * Tq;                         // 262144 tokens
constexpr float LOSS_SCALE = 0.25f / (float)(Bq * Tq * Dq);

typedef __attribute__((ext_vector_type(8))) short short8;   // 8 bf16 (4 VGPRs)
typedef __attribute__((ext_vector_type(4))) float f32x4;
typedef __attribute__((ext_vector_type(4))) unsigned int u32x4;

// Round 14: R13 MFMA structure with the rescan-rate fix.
// R13 was correct (absmax unchanged -> codes exact) but its margin
// (1e-4*rn + 5e-3) was ~gap-sized -> ~10-40% of tokens took the 1024-k
// global exact rescan, dominating runtime. Provable bound: d2 err <=
// 7.6e-6*(rn+cn) (Dekker bf16 split; bf16 products exact in fp32), so
// margin = 8e-5*(rn+cnmax) is a 5x cushion -> ~1% flag rate.
// Also: d2' = fmaf(acc,-2,cn) (rn const per token; ordering preserved to
// within margin slack; exact rescan decides all flagged cases), and a
// tightened 5-op top-2 update. Everything else identical to passing R13.
// C/D layout (m89-verified): col = lane&15, row = (lane>>4)*4 + reg.
__global__ __launch_bounds__(512, 2)
void rvq_main(const float* __restrict__ x,
              const float* __restrict__ codebooks,
              const float* __restrict__ post_scale,
              const float* __restrict__ post_bias,
              const float* __restrict__ conv_w,
              const float* __restrict__ conv_b,
              float* __restrict__ out)
{
    __shared__ __align__(16) float s_frag[Kq * 8];  // 32 KB: per cw, bf16x8 hi | bf16x8 lo
    __shared__ float s_cn[Kq];                      // 4 KB fp32 norms
    __shared__ float s_red[8];                      // per-wave cn max

    const int tid  = threadIdx.x;                  // 0..511
    const int lane = tid & 63;
    const int wave = tid >> 6;                     // 0..7
    const int quad = lane >> 4;                    // 0..3  (K-group)
    const int col  = lane & 15;                    // MFMA n / token idx
    const int selo = quad >> 1;                    // B half: 0=hi(ch) 1=lo(cl)
    const int wbase = blockIdx.x * 256 + wave * 32;

    // residuals: lane owns token wbase + g*16 + col for g=0,1 (dup x4 quads)
    float rg[2][Dq];
#pragma unroll
    for (int g = 0; g < 2; ++g) {
        const float4* xp = reinterpret_cast<const float4*>(
            x + (size_t)(wbase + g * 16 + col) * Dq);
        float4 a = xp[0], b = xp[1];
        rg[g][0]=a.x; rg[g][1]=a.y; rg[g][2]=a.z; rg[g][3]=a.w;
        rg[g][4]=b.x; rg[g][5]=b.y; rg[g][6]=b.z; rg[g][7]=b.w;
    }

    float qso[2][Dq];
#pragma unroll
    for (int g = 0; g < 2; ++g)
#pragma unroll
        for (int d = 0; d < Dq; ++d) qso[g][d] = 0.0f;
    float lossacc = 0.0f;

    float* out_quant = out;                               // [B*T*D]
    float* out_loss  = out + (size_t)NTOK * Dq;           // [1]
    float* out_codes = out_loss + 1;                      // [Q*B*T] as float

    for (int q = 0; q < Qq; ++q) {
        const float* cbq = codebooks + (size_t)q * Kq * Dq;

        // ---- stage: bf16 hi/lo B-fragments + fp32 norms (np order) ----
        float nmax = 0.0f;
#pragma unroll
        for (int it = 0; it < 2; ++it) {
            int n = tid + it * 512;
            const float4* cp = reinterpret_cast<const float4*>(cbq + (size_t)n * 8);
            float4 ca = cp[0], cc = cp[1];
            float c[8] = {ca.x, ca.y, ca.z, ca.w, cc.x, cc.y, cc.z, cc.w};
            float nn = __fmul_rn(c[0], c[0]);
#pragma unroll
            for (int d = 1; d < 8; ++d)
                nn = __fadd_rn(nn, __fmul_rn(c[d], c[d]));
            s_cn[n] = nn;
            nmax = fmaxf(nmax, nn);
            unsigned hb[8], lb[8];
#pragma unroll
            for (int d = 0; d < 8; ++d) {
                union { float f; unsigned u; } v; v.f = c[d];
                hb[d] = (v.u + 0x7FFFu + ((v.u >> 16) & 1u)) >> 16;   // RNE bf16
                union { unsigned u; float f; } h; h.u = hb[d] << 16;
                union { float f; unsigned u; } w; w.f = __fsub_rn(c[d], h.f); // exact
                lb[d] = (w.u + 0x7FFFu + ((w.u >> 16) & 1u)) >> 16;
            }
            u32x4 wh = {hb[0] | (hb[1] << 16), hb[2] | (hb[3] << 16),
                        hb[4] | (hb[5] << 16), hb[6] | (hb[7] << 16)};
            u32x4 wl = {lb[0] | (lb[1] << 16), lb[2] | (lb[3] << 16),
                        lb[4] | (lb[5] << 16), lb[6] | (lb[7] << 16)};
            reinterpret_cast<u32x4*>(s_frag)[n * 2]     = wh;
            reinterpret_cast<u32x4*>(s_frag)[n * 2 + 1] = wl;
        }
#pragma unroll
        for (int off = 32; off >= 1; off >>= 1)
            nmax = fmaxf(nmax, __shfl_xor(nmax, off, 64));
        if (lane == 0) s_red[wave] = nmax;
        __syncthreads();
        float cnmax = s_red[0];
#pragma unroll
        for (int i = 1; i < 8; ++i) cnmax = fmaxf(cnmax, s_red[i]);

        // ---- per-lane prep: rn (np order), split, A-fragments ----
        float rn_own[2];
        short8 afrag[2];
#pragma unroll
        for (int g = 0; g < 2; ++g) {
            float n = __fmul_rn(rg[g][0], rg[g][0]);
#pragma unroll
            for (int d = 1; d < 8; ++d)
                n = __fadd_rn(n, __fmul_rn(rg[g][d], rg[g][d]));
            rn_own[g] = n;
            short8 af;
#pragma unroll
            for (int d = 0; d < 8; ++d) {
                union { float f; unsigned u; } v; v.f = rg[g][d];
                unsigned hbb = (v.u + 0x7FFFu + ((v.u >> 16) & 1u)) >> 16;
                union { unsigned u; float f; } h; h.u = hbb << 16;
                union { float f; unsigned u; } w; w.f = __fsub_rn(rg[g][d], h.f);
                unsigned lbb = (w.u + 0x7FFFu + ((w.u >> 16) & 1u)) >> 16;
                af[d] = (short)((quad & 1) ? lbb : hbb);   // A: odd quads = lo
            }
            afrag[g] = af;
        }
        float s_rnv[2][4];        // rn of token row = quad*4 + reg
#pragma unroll
        for (int g = 0; g < 2; ++g)
#pragma unroll
            for (int rr = 0; rr < 4; ++rr)
                s_rnv[g][rr] = __shfl(rn_own[g], quad * 4 + rr, 64);

        // ---- MFMA tile loop: 64 tiles of 16 cw; 2 token-groups per B-load ----
        // d2' = cn - 2*dot (rn folded out; ordering preserved within margin)
        float b1[2][4], b2[2][4];
        int   k1[2][4];
#pragma unroll
        for (int g = 0; g < 2; ++g)
#pragma unroll
            for (int rr = 0; rr < 4; ++rr) {
                b1[g][rr] = __builtin_inff(); b2[g][rr] = __builtin_inff();
                k1[g][rr] = 0;
            }

        const f32x4* fragp = reinterpret_cast<const f32x4*>(s_frag);
#pragma unroll 2
        for (int tile = 0; tile < Kq / 16; ++tile) {
            f32x4 braw = fragp[(tile * 16 + col) * 2 + selo];
            short8 bfrag = __builtin_bit_cast(short8, braw);
            float cnv = s_cn[tile * 16 + col];
            int cand = tile * 16 + col;
#pragma unroll
            for (int g = 0; g < 2; ++g) {
                f32x4 acc = {0.f, 0.f, 0.f, 0.f};
                acc = __builtin_amdgcn_mfma_f32_16x16x32_bf16(afrag[g], bfrag, acc, 0, 0, 0);
#pragma unroll
                for (int reg = 0; reg < 4; ++reg) {
                    float d2 = fmaf(acc[reg], -2.0f, cnv);
                    bool c1 = d2 < b1[g][reg];
                    float nb2 = c1 ? b1[g][reg] : fminf(b2[g][reg], d2);
                    k1[g][reg] = c1 ? cand : k1[g][reg];
                    b1[g][reg] = fminf(b1[g][reg], d2);
                    b2[g][reg] = nb2;
                }
            }
        }

        // ---- merge 16 cols per token (lex (d2,k)); flag near-ties ----
        int kf[2][4];
#pragma unroll
        for (int g = 0; g < 2; ++g)
#pragma unroll
            for (int reg = 0; reg < 4; ++reg) {
                float B1 = b1[g][reg], B2 = b2[g][reg];
                int K1 = k1[g][reg];
#pragma unroll
                for (int m = 1; m <= 8; m <<= 1) {
                    float o1 = __shfl_xor(B1, m, 64);
                    float o2 = __shfl_xor(B2, m, 64);
                    int   ok = __shfl_xor(K1, m, 64);
                    bool ow = (o1 < B1) || (o1 == B1 && ok < K1);
                    float nb2 = ow ? fminf(B1, o2) : fminf(o1, B2);
                    B1 = ow ? o1 : B1; K1 = ow ? ok : K1; B2 = nb2;
                }
                // margin: 5x the provable split-error bound (covers exact ties)
                float margin = (s_rnv[g][reg] + cnmax) * 8e-5f;
                bool flg = (B2 <= B1 + margin);
                kf[g][reg] = K1 | (flg ? (int)0x80000000 : 0);
            }

        // ---- route result to owner lanes (token idx == col) ----
        int bk[2], fl[2];
#pragma unroll
        for (int g = 0; g < 2; ++g) {
            int src = (col >> 2) * 16;     // quad-group holding rows col&~3
            int t0 = __shfl(kf[g][0], src, 64);
            int t1 = __shfl(kf[g][1], src, 64);
            int t2 = __shfl(kf[g][2], src, 64);
            int t3 = __shfl(kf[g][3], src, 64);
            int ta = (col & 1) ? t1 : t0;
            int tb = (col & 1) ? t3 : t2;
            int tv = (col & 2) ? tb : ta;
            fl[g] = (tv >> 31) & 1;
            bk[g] = tv & 0x7FFFFFFF;
        }

        // ---- rare (~1%): wave-cooperative EXACT rescan (bit-exact R12 chain) ----
#pragma unroll
        for (int g = 0; g < 2; ++g) {
            unsigned long long msk = __ballot(fl[g] && (lane < 16));
            while (msk) {
                int p = __builtin_ctzll(msk); msk &= (msk - 1);
                float rt[8];
#pragma unroll
                for (int d = 0; d < 8; ++d) rt[d] = __shfl(rg[g][d], p, 64);
                float rnt = __shfl(rn_own[g], p, 64);
                float bb = __builtin_inff(); int bkk = 0;
#pragma unroll 2
                for (int i = 0; i < 16; ++i) {
                    int k = lane + 64 * i;
                    const float4* cp = reinterpret_cast<const float4*>(cbq + (size_t)k * 8);
                    float4 ca = cp[0], cc = cp[1];
                    float dot = __fmul_rn(rt[0], ca.x);
                    dot = fmaf(rt[1], ca.y, dot);
                    dot = fmaf(rt[2], ca.z, dot);
                    dot = fmaf(rt[3], ca.w, dot);
                    dot = fmaf(rt[4], cc.x, dot);
                    dot = fmaf(rt[5], cc.y, dot);
                    dot = fmaf(rt[6], cc.z, dot);
                    dot = fmaf(rt[7], cc.w, dot);
                    float d2 = fmaf(dot, -2.0f, __fadd_rn(rnt, s_cn[k]));
                    if (d2 < bb) { bb = d2; bkk = k; }     // k ascending in-lane
                }
#pragma unroll
                for (int mm = 1; mm <= 32; mm <<= 1) {
                    float ob = __shfl_xor(bb, mm, 64);
                    int   ok = __shfl_xor(bkk, mm, 64);
                    if (ob < bb || (ob == bb && ok < bkk)) { bb = ob; bkk = ok; }
                }
                if (col == p) bk[g] = bkk;                 // np first-min, exact
            }
        }

        // ---- codes, exact update (np chains, fp32 codebook from global) ----
        const float sc = post_scale[q];
        const float bi = post_bias[q];
#pragma unroll
        for (int g = 0; g < 2; ++g) {
            if (lane < 16)
                out_codes[(size_t)q * NTOK + wbase + g * 16 + col] = (float)bk[g];
            const float4* ep = reinterpret_cast<const float4*>(cbq + (size_t)bk[g] * 8);
            float4 ea = ep[0], eb = ep[1];
            float e[8] = {ea.x, ea.y, ea.z, ea.w, eb.x, eb.y, eb.z, eb.w};
#pragma unroll
            for (int d = 0; d < 8; ++d) {
                float rd = rg[g][d];
                float est = __fadd_rn(rd, __fsub_rn(e[d], rd));
                qso[g][d] = __fadd_rn(__fadd_rn(qso[g][d], __fmul_rn(est, sc)), bi);
                float nr = __fsub_rn(rd, e[d]);
                float df = __fsub_rn(nr, e[d]);
                if (lane < 16) lossacc = fmaf(df, df, lossacc);
                rg[g][d] = nr;
            }
        }
        __syncthreads();   // all s_frag/s_cn/s_red reads done before next q
    }

    // ---- 1x1 conv epilogue: owner lanes (lane<16) write their 2 tokens ----
    if (lane < 16) {
#pragma unroll
        for (int g = 0; g < 2; ++g) {
            float o[8];
#pragma unroll
            for (int e2 = 0; e2 < 8; ++e2) {
                float acc = __fmul_rn(qso[g][0], conv_w[e2 * 8 + 0]);
#pragma unroll
                for (int d = 1; d < 8; ++d)
                    acc = fmaf(qso[g][d], conv_w[e2 * 8 + d], acc);
                o[e2] = __fadd_rn(acc, conv_b[e2]);
            }
            float4* op = reinterpret_cast<float4*>(
                out_quant + (size_t)(wbase + g * 16 + col) * Dq);
            op[0] = make_float4(o[0], o[1], o[2], o[3]);
            op[1] = make_float4(o[4], o[5], o[6], o[7]);
        }
    }

    // ---- loss reduction (lane<16 contributed; rest are 0) ----
    float v = lossacc;
#pragma unroll
    for (int off = 32; off >= 1; off >>= 1)
        v += __shfl_xor(v, off, 64);
    if (lane == 0)
        atomicAdd(out_loss, v * LOSS_SCALE);
}

extern "C" void kernel_launch(void* const* d_in, const int* in_sizes, int n_in,
                              void* d_out, int out_size, void* d_ws, size_t ws_size,
                              hipStream_t stream) {
    const float* x     = (const float*)d_in[0];
    const float* cb    = (const float*)d_in[1];
    const float* ps    = (const float*)d_in[2];
    const float* pb    = (const float*)d_in[3];
    const float* cw    = (const float*)d_in[4];
    const float* cbias = (const float*)d_in[5];
    float* out = (float*)d_out;

    // zero the loss accumulator slot (d_out is poisoned before every call)
    hipMemsetAsync(out + (size_t)NTOK * Dq, 0, sizeof(float), stream);

    rvq_main<<<dim3(NTOK / 256), dim3(512), 0, stream>>>(
        x, cb, ps, pb, cw, cbias, out);
}

// Round 15
// 552.452 us; speedup vs baseline: 1.5581x; 1.4610x over previous
//
#include <hip/hip_runtime.h>
#include <math.h>

// Problem constants (from reference setup_inputs)
constexpr int Bq = 32;
constexpr int Tq = 8192;
constexpr int Dq = 8;
constexpr int Qq = 8;
constexpr int Kq = 1024;
constexpr int NTOK = Bq * Tq;                         // 262144 tokens
constexpr float LOSS_SCALE = 0.25f / (float)(Bq * Tq * Dq);

typedef __attribute__((ext_vector_type(8))) short short8;   // 8 bf16 (4 VGPRs)
typedef __attribute__((ext_vector_type(4))) float f32x4;
typedef __attribute__((ext_vector_type(4))) unsigned int u32x4;

// Round 15: transposed MFMA (codewords = C rows, tokens = C cols) + cn folded
// into the accumulator init. vs R14: (a) token results stay in one lane
// column -> merge is 2 shfl stages, no routing; (b) acc init = -cn/2 gives
// D = dot - cn/2, argmin d2 == argmax D, no per-candidate fma; (c) A-frag
// via 2x ds_read_b64 (2-way alias = free) not 4-way b128; cn-init loads are
// 4-address broadcasts (free). Top-2-max: m2 = max(m2, min(m1, D)).
// Numerics: Dekker bf16 split (R13/14-proven, |D err| <= ~1e-5*(rn+cn));
// margin_D = 4e-5*(rn+cnmax) (== R14's passing d2 margin); flagged tokens
// take the R13-proven wave-cooperative EXACT rescan (seq mul/fma np chain,
// cn recomputed np-order) -> np.argmin first-min semantics unconditionally.
// Operand mapping (validated by R13 passing): first mfma arg entity keyed by
// lane&15 -> C row; second arg entity keyed by lane&15 -> C col; k-group =
// lane>>4 for both. A(cw) k-groups: ch,cl,ch,cl (sel quad&1); B(tok):
// rh,rh,rl,rl (sel quad>>1) -> all 4 cross terms.
__global__ __launch_bounds__(512, 2)
void rvq_main(const float* __restrict__ x,
              const float* __restrict__ codebooks,
              const float* __restrict__ post_scale,
              const float* __restrict__ post_bias,
              const float* __restrict__ conv_w,
              const float* __restrict__ conv_b,
              float* __restrict__ out)
{
    __shared__ __align__(16) unsigned s_frag[Kq * 8];  // 32 KB: cw n -> [ch x8bf16 | cl x8bf16]
    __shared__ __align__(16) float s_cnh[Kq];          // -cn/2
    __shared__ float s_red[8];                         // per-wave cn max

    const int tid  = threadIdx.x;                  // 0..511
    const int lane = tid & 63;
    const int wave = tid >> 6;                     // 0..7
    const int quad = lane >> 4;                    // 0..3 (k-group)
    const int col  = lane & 15;                    // token index (C col)
    const int wbase = blockIdx.x * 256 + wave * 32;

    // residuals: token wbase + g*16 + col, g=0,1 (all 4 quads duplicate)
    float rg[2][Dq];
#pragma unroll
    for (int g = 0; g < 2; ++g) {
        const float4* xp = reinterpret_cast<const float4*>(
            x + (size_t)(wbase + g * 16 + col) * Dq);
        float4 a = xp[0], b = xp[1];
        rg[g][0]=a.x; rg[g][1]=a.y; rg[g][2]=a.z; rg[g][3]=a.w;
        rg[g][4]=b.x; rg[g][5]=b.y; rg[g][6]=b.z; rg[g][7]=b.w;
    }

    // owner: quad<2 owns token wbase + quad*16 + col (g == quad)
    float qso[Dq];
#pragma unroll
    for (int d = 0; d < Dq; ++d) qso[d] = 0.0f;
    float lossacc = 0.0f;

    float* out_quant = out;                               // [B*T*D]
    float* out_loss  = out + (size_t)NTOK * Dq;           // [1]
    float* out_codes = out_loss + 1;                      // [Q*B*T] as float

    for (int q = 0; q < Qq; ++q) {
        const float* cbq = codebooks + (size_t)q * Kq * Dq;

        // ---- stage: per cw, bf16 ch|cl fragments, -cn/2, cnmax ----
        float nmax = 0.0f;
#pragma unroll
        for (int it = 0; it < 2; ++it) {
            int n = tid + it * 512;
            const float4* cp = reinterpret_cast<const float4*>(cbq + (size_t)n * 8);
            float4 ca = cp[0], cc = cp[1];
            float c[8] = {ca.x, ca.y, ca.z, ca.w, cc.x, cc.y, cc.z, cc.w};
            float nn = __fmul_rn(c[0], c[0]);
#pragma unroll
            for (int d = 1; d < 8; ++d)
                nn = __fadd_rn(nn, __fmul_rn(c[d], c[d]));
            s_cnh[n] = -0.5f * nn;                 // exact scale
            nmax = fmaxf(nmax, nn);
            unsigned hb[8], lb[8];
#pragma unroll
            for (int d = 0; d < 8; ++d) {
                union { float f; unsigned u; } v; v.f = c[d];
                hb[d] = (v.u + 0x7FFFu + ((v.u >> 16) & 1u)) >> 16;   // RNE bf16
                union { unsigned u; float f; } h; h.u = hb[d] << 16;
                union { float f; unsigned u; } w; w.f = __fsub_rn(c[d], h.f);
                lb[d] = (w.u + 0x7FFFu + ((w.u >> 16) & 1u)) >> 16;
            }
            u32x4 wh = {hb[0] | (hb[1] << 16), hb[2] | (hb[3] << 16),
                        hb[4] | (hb[5] << 16), hb[6] | (hb[7] << 16)};
            u32x4 wl = {lb[0] | (lb[1] << 16), lb[2] | (lb[3] << 16),
                        lb[4] | (lb[5] << 16), lb[6] | (lb[7] << 16)};
            reinterpret_cast<u32x4*>(s_frag)[n * 2]     = wh;   // ch
            reinterpret_cast<u32x4*>(s_frag)[n * 2 + 1] = wl;   // cl
        }
#pragma unroll
        for (int off = 32; off >= 1; off >>= 1)
            nmax = fmaxf(nmax, __shfl_xor(nmax, off, 64));
        if (lane == 0) s_red[wave] = nmax;
        __syncthreads();
        float cnmax = s_red[0];
#pragma unroll
        for (int i = 1; i < 8; ++i) cnmax = fmaxf(cnmax, s_red[i]);

        // ---- per-lane: rn (np order) + token B-fragments (rh,rh,rl,rl) ----
        float rn_own[2];
        short8 bfrag[2];
#pragma unroll
        for (int g = 0; g < 2; ++g) {
            float n = __fmul_rn(rg[g][0], rg[g][0]);
#pragma unroll
            for (int d = 1; d < 8; ++d)
                n = __fadd_rn(n, __fmul_rn(rg[g][d], rg[g][d]));
            rn_own[g] = n;
            short8 bf;
#pragma unroll
            for (int d = 0; d < 8; ++d) {
                union { float f; unsigned u; } v; v.f = rg[g][d];
                unsigned hbb = (v.u + 0x7FFFu + ((v.u >> 16) & 1u)) >> 16;
                union { unsigned u; float f; } h; h.u = hbb << 16;
                union { float f; unsigned u; } w; w.f = __fsub_rn(rg[g][d], h.f);
                unsigned lbb = (w.u + 0x7FFFu + ((w.u >> 16) & 1u)) >> 16;
                bf[d] = (short)((quad >> 1) ? lbb : hbb);  // q0,q1=rh; q2,q3=rl
            }
            bfrag[g] = bf;
        }

        // ---- main loop: 64 tiles x 16 cw; lane tracks top-2 MAX of D ----
        float m1[2] = {-__builtin_inff(), -__builtin_inff()};
        float m2[2] = {-__builtin_inff(), -__builtin_inff()};
        int   k1[2] = {0, 0};
        const int fsel = (quad & 1) * 4;               // A half: ch / cl
        const int quad4 = quad * 4;
#pragma unroll 2
        for (int tile = 0; tile < Kq / 16; ++tile) {
            f32x4 cinit = *reinterpret_cast<const f32x4*>(s_cnh + tile * 16 + quad4);
            int fb = (tile * 16 + col) * 8 + fsel;     // u32 units
            uint2 w0 = *reinterpret_cast<const uint2*>(s_frag + fb);
            uint2 w1 = *reinterpret_cast<const uint2*>(s_frag + fb + 2);
            u32x4 wa = {w0.x, w0.y, w1.x, w1.y};
            short8 afrag = __builtin_bit_cast(short8, wa);
            int candb = tile * 16 + quad4;
#pragma unroll
            for (int g = 0; g < 2; ++g) {
                f32x4 acc = cinit;                     // D = dot - cn/2
                acc = __builtin_amdgcn_mfma_f32_16x16x32_bf16(afrag, bfrag[g], acc, 0, 0, 0);
#pragma unroll
                for (int reg = 0; reg < 4; ++reg) {
                    float D = acc[reg];
                    bool c = D > m1[g];                // strict: first max = lowest k
                    m2[g] = fmaxf(m2[g], fminf(m1[g], D));   // runner-up
                    k1[g] = c ? (candb + reg) : k1[g];
                    m1[g] = fmaxf(m1[g], D);
                }
            }
        }

        // ---- merge 4 quads per token col (lex: D desc, k asc); flag ties ----
        int bk[2], fl[2];
#pragma unroll
        for (int g = 0; g < 2; ++g) {
            float M1 = m1[g], M2 = m2[g]; int K1 = k1[g];
#pragma unroll
            for (int m = 16; m <= 32; m <<= 1) {
                float o1 = __shfl_xor(M1, m, 64);
                float o2 = __shfl_xor(M2, m, 64);
                int   ok = __shfl_xor(K1, m, 64);
                bool ow = (o1 > M1) || (o1 == M1 && ok < K1);
                M2 = ow ? fmaxf(M1, o2) : fmaxf(o1, M2);
                M1 = ow ? o1 : M1; K1 = ow ? ok : K1;
            }
            float margin = (rn_own[g] + cnmax) * 4e-5f;   // 4x provable bound
            fl[g] = (__fsub_rn(M1, M2) <= margin) ? 1 : 0;
            bk[g] = K1;
        }

        // ---- rare: wave-cooperative EXACT rescan (np chain, first-min) ----
#pragma unroll
        for (int g = 0; g < 2; ++g) {
            unsigned long long msk = __ballot(fl[g] && (quad == g));
            while (msk) {
                int p = __builtin_ctzll(msk); msk &= (msk - 1);
                float rt[8];
#pragma unroll
                for (int d = 0; d < 8; ++d) rt[d] = __shfl(rg[g][d], p, 64);
                float rnt = __shfl(rn_own[g], p, 64);
                float bb = __builtin_inff(); int bkk = 0;
#pragma unroll 2
                for (int i = 0; i < 16; ++i) {
                    int k = lane + 64 * i;
                    const float4* cp = reinterpret_cast<const float4*>(cbq + (size_t)k * 8);
                    float4 ca = cp[0], cc = cp[1];
                    float c8[8] = {ca.x, ca.y, ca.z, ca.w, cc.x, cc.y, cc.z, cc.w};
                    float cn = __fmul_rn(c8[0], c8[0]);          // np-order cn
#pragma unroll
                    for (int d = 1; d < 8; ++d)
                        cn = __fadd_rn(cn, __fmul_rn(c8[d], c8[d]));
                    float dot = __fmul_rn(rt[0], c8[0]);
                    dot = fmaf(rt[1], c8[1], dot);
                    dot = fmaf(rt[2], c8[2], dot);
                    dot = fmaf(rt[3], c8[3], dot);
                    dot = fmaf(rt[4], c8[4], dot);
                    dot = fmaf(rt[5], c8[5], dot);
                    dot = fmaf(rt[6], c8[6], dot);
                    dot = fmaf(rt[7], c8[7], dot);
                    float d2 = fmaf(dot, -2.0f, __fadd_rn(rnt, cn));
                    if (d2 < bb) { bb = d2; bkk = k; }           // k asc in-lane
                }
#pragma unroll
                for (int mm = 1; mm <= 32; mm <<= 1) {
                    float ob = __shfl_xor(bb, mm, 64);
                    int   ok = __shfl_xor(bkk, mm, 64);
                    if (ob < bb || (ob == bb && ok < bkk)) { bb = ob; bkk = ok; }
                }
                if (col == (p & 15)) bk[g] = bkk;      // all quads of token p
            }
        }

        // ---- codes + exact update (np chains; embed from L2-hot global) ----
        const float sc = post_scale[q];
        const float bi = post_bias[q];
#pragma unroll
        for (int g = 0; g < 2; ++g) {
            if (quad == g)
                out_codes[(size_t)q * NTOK + wbase + g * 16 + col] = (float)bk[g];
            const float4* ep = reinterpret_cast<const float4*>(cbq + (size_t)bk[g] * 8);
            float4 ea = ep[0], eb = ep[1];
            float e[8] = {ea.x, ea.y, ea.z, ea.w, eb.x, eb.y, eb.z, eb.w};
#pragma unroll
            for (int d = 0; d < 8; ++d) {
                float rd = rg[g][d];
                float est = __fadd_rn(rd, __fsub_rn(e[d], rd));
                if (quad == g) {
                    qso[d] = __fadd_rn(__fadd_rn(qso[d], __fmul_rn(est, sc)), bi);
                }
                float nr = __fsub_rn(rd, e[d]);
                float df = __fsub_rn(nr, e[d]);
                if (quad == g) lossacc = fmaf(df, df, lossacc);
                rg[g][d] = nr;
            }
        }
        __syncthreads();   // s_frag/s_cnh/s_red reads done before next q
    }

    // ---- 1x1 conv epilogue: owner lanes (quad<2) write their token ----
    if (quad < 2) {
        float o[8];
#pragma unroll
        for (int e2 = 0; e2 < 8; ++e2) {
            float acc = __fmul_rn(qso[0], conv_w[e2 * 8 + 0]);
#pragma unroll
            for (int d = 1; d < 8; ++d)
                acc = fmaf(qso[d], conv_w[e2 * 8 + d], acc);
            o[e2] = __fadd_rn(acc, conv_b[e2]);
        }
        float4* op = reinterpret_cast<float4*>(
            out_quant + (size_t)(wbase + quad * 16 + col) * Dq);
        op[0] = make_float4(o[0], o[1], o[2], o[3]);
        op[1] = make_float4(o[4], o[5], o[6], o[7]);
    }

    // ---- loss reduction (owner lanes contributed; rest are 0) ----
    float v = lossacc;
#pragma unroll
    for (int off = 32; off >= 1; off >>= 1)
        v += __shfl_xor(v, off, 64);
    if (lane == 0)
        atomicAdd(out_loss, v * LOSS_SCALE);
}

extern "C" void kernel_launch(void* const* d_in, const int* in_sizes, int n_in,
                              void* d_out, int out_size, void* d_ws, size_t ws_size,
                              hipStream_t stream) {
    const float* x     = (const float*)d_in[0];
    const float* cb    = (const float*)d_in[1];
    const float* ps    = (const float*)d_in[2];
    const float* pb    = (const float*)d_in[3];
    const float* cw    = (const float*)d_in[4];
    const float* cbias = (const float*)d_in[5];
    float* out = (float*)d_out;

    // zero the loss accumulator slot (d_out is poisoned before every call)
    hipMemsetAsync(out + (size_t)NTOK * Dq, 0, sizeof(float), stream);

    rvq_main<<<dim3(NTOK / 256), dim3(512), 0, stream>>>(
        x, cb, ps, pb, cw, cbias, out);
}